// Round 7
// baseline (209.028 us; speedup 1.0000x reference)
//
#include <hip/hip_runtime.h>
#include <hip/hip_bf16.h>

// RelativeSemanticLoss via bf16 MFMA GEMM + fused softmax-NLL epilogue.
// R7: LDS-pressure attack on R4 structure:
//  (a) cls fragments read straight from L2 into registers (no LDS staging),
//  (b) pred LDS XOR-swizzled (pre-swizzled global src, rule #21) -> 2-way free.

#define NUM_CLS 150
#define NT_TILES 10      // 160 padded classes
#define D_DIM   512
#define HW_DIM  65536
#define IGNORE_L 255

typedef __attribute__((ext_vector_type(8))) short bf16x8;
typedef __attribute__((ext_vector_type(4))) float f32x4;
typedef __attribute__((ext_vector_type(4))) unsigned int u32x4;

#define GLOAD16(gsrc, ldst) \
    __builtin_amdgcn_global_load_lds((const __attribute__((address_space(1))) void*)(gsrc), \
                                     (__attribute__((address_space(3))) void*)(ldst), 16, 0, 0)

static __device__ __forceinline__ short f2bf(float f) {
    __hip_bfloat16 h = __float2bfloat16(f);   // RNE
    return __builtin_bit_cast(short, h);
}

// Pack cls (150x512 fp32) -> bf16 fragments in lane-linear order:
// packed[(s*10+nt)*512 + l*8 + j] (ushort) = bf16(cls[nt*16+(l&15)][s*32+(l>>4)*8+j])
// Also zeroes the ws accumulators.
__global__ void rsl_pack_cls(const float* __restrict__ cls,
                             unsigned short* __restrict__ packed,
                             double* __restrict__ ws_sum,
                             unsigned long long* __restrict__ ws_cnt)
{
    int t = blockIdx.x * 256 + threadIdx.x;      // 0 .. 16*10*64-1
    if (t == 0) { ws_sum[0] = 0.0; ws_cnt[0] = 0ull; }
    if (t >= 16 * NT_TILES * 64) return;
    int s  = t / (NT_TILES * 64);
    int r  = t - s * (NT_TILES * 64);
    int nt = r >> 6;
    int l  = r & 63;
    int c  = nt * 16 + (l & 15);
    int k  = s * 32 + (l >> 4) * 8;
    unsigned short v[8];
#pragma unroll
    for (int j = 0; j < 8; ++j)
        v[j] = (c < NUM_CLS) ? (unsigned short)f2bf(cls[c * D_DIM + k + j]) : (unsigned short)0;
    u32x4 w;
#pragma unroll
    for (int q = 0; q < 4; ++q)
        w[q] = (unsigned int)v[2 * q] | ((unsigned int)v[2 * q + 1] << 16);
    *(u32x4*)(packed + (size_t)(s * NT_TILES + nt) * 512 + (size_t)l * 8) = w;
}

__global__ __launch_bounds__(256, 3)
void rsl_mfma(const float* __restrict__ pred,
              const unsigned short* __restrict__ packed,
              const int*   __restrict__ idx,
              const int*   __restrict__ lut,
              double* __restrict__ ws_sum,
              unsigned long long* __restrict__ ws_cnt)
{
    // LDS: pred tile [32 dims][128 pixels] fp32, double-buffered = 32 KB.
    // Swizzled layout: element [d][p] lives at [d][p ^ ((d>>3)<<3)].
    __shared__ float sP[2][32][128];

    const int lane = threadIdx.x & 63;
    const int wid  = threadIdx.x >> 6;
    const int row  = lane & 15;      // M-idx in tile (A frag) / N-idx (C/D)
    const int g    = lane >> 4;      // k-group (A frag) / row-group (C/D)

    const int pixbase = blockIdx.x * 128;            // never straddles b (65536%128==0)
    const int b  = pixbase >> 16;
    const int p0 = pixbase & 0xFFFF;
    const float* predb = pred + (size_t)b * D_DIM * HW_DIM;
    // staging: instruction t covers dims {2t + (lane>>5)}, pixels 4*(lane&31)..+3;
    // global pixel offset pre-swizzled by (t>>2)<<3 so linear LDS = swizzled layout.
    const int pxl = (lane & 31) * 4;
    const int dl  = lane >> 5;

    f32x4 acc[2][NT_TILES] = {};

    // ---- prologue: stage s=0 pred ----
#pragma unroll
    for (int tt = 0; tt < 4; ++tt) {
        const int t = wid * 4 + tt;              // dim pair index 0..15
        GLOAD16(predb + (size_t)(2 * t + dl) * HW_DIM + (p0 + (pxl ^ ((t >> 2) << 3))),
                &sP[0][2 * t][0]);
    }
    __syncthreads();

    for (int s = 0; s < 16; ++s) {
        const int cur = s & 1;
        // ---- stage s+1 pred into the other buffer (async DMA) ----
        if (s < 15) {
            const float* srcb = predb + (size_t)((s + 1) * 32) * HW_DIM;
#pragma unroll
            for (int tt = 0; tt < 4; ++tt) {
                const int t = wid * 4 + tt;
                GLOAD16(srcb + (size_t)(2 * t + dl) * HW_DIM + (p0 + (pxl ^ ((t >> 2) << 3))),
                        &sP[cur ^ 1][2 * t][0]);
            }
        }

        // ---- pred fragments from swizzled LDS (2-way conflict = free) ----
        bf16x8 pf[2];
#pragma unroll
        for (int mt = 0; mt < 2; ++mt)
#pragma unroll
            for (int j = 0; j < 8; ++j)
                pf[mt][j] = f2bf(sP[cur][g * 8 + j][(wid * 32 + mt * 16 + row) ^ (g << 3)]);

        // ---- cls fragments straight from L2 (packed is 160 KB, L2-resident) ----
        const unsigned short* cb = packed + (size_t)(s * NT_TILES) * 512 + (size_t)lane * 8;
#pragma unroll
        for (int nt = 0; nt < NT_TILES; ++nt) {
            bf16x8 cf = *(const bf16x8*)(cb + nt * 512);
#pragma unroll
            for (int mt = 0; mt < 2; ++mt)
                acc[mt][nt] = __builtin_amdgcn_mfma_f32_16x16x32_bf16(pf[mt], cf, acc[mt][nt], 0, 0, 0);
        }
        __syncthreads();   // drain: next pred tile ready, buffer safe to overwrite
    }

    // ---- epilogue. C/D: class = nt*16 + row, pixel = wid*32 + mt*16 + g*4 + j ----
    const float invT = 1.0f / 0.07f;
    float local_sum = 0.f;
    int   local_cnt = 0;
#pragma unroll
    for (int mt = 0; mt < 2; ++mt) {
#pragma unroll
        for (int j = 0; j < 4; ++j) {
            const int pixg = pixbase + wid * 32 + mt * 16 + g * 4 + j;
            const int lab  = lut[idx[pixg]];
            const bool valid = (lab != IGNORE_L);

            float m = -1e30f;
#pragma unroll
            for (int nt = 0; nt < NT_TILES; ++nt) {
                int c = nt * 16 + row;
                float v = (c < NUM_CLS) ? acc[mt][nt][j] : -1e30f;
                m = fmaxf(m, v);
            }
#pragma unroll
            for (int o = 8; o >= 1; o >>= 1) m = fmaxf(m, __shfl_xor(m, o));

            float ssum = 0.f, slab = 0.f;
#pragma unroll
            for (int nt = 0; nt < NT_TILES; ++nt) {
                int c = nt * 16 + row;
                if (c < NUM_CLS) {
                    float v = acc[mt][nt][j];
                    ssum += __expf((v - m) * invT);
                    slab += (c == lab) ? v : 0.f;
                }
            }
#pragma unroll
            for (int o = 8; o >= 1; o >>= 1) {
                ssum += __shfl_xor(ssum, o);
                slab += __shfl_xor(slab, o);
            }
            if (row == 0 && valid) {
                local_sum += (m - slab) * invT + __logf(ssum);
                local_cnt += 1;
            }
        }
    }

    // wave(64) reduce -> block -> global atomics
#pragma unroll
    for (int o = 32; o >= 1; o >>= 1) {
        local_sum += __shfl_down(local_sum, o);
        local_cnt += __shfl_down(local_cnt, o);
    }
    __shared__ float sv[4];
    __shared__ int   sc[4];
    if (lane == 0) { sv[wid] = local_sum; sc[wid] = local_cnt; }
    __syncthreads();
    if (threadIdx.x == 0) {
        float tv = sv[0] + sv[1] + sv[2] + sv[3];
        int   tc = sc[0] + sc[1] + sc[2] + sc[3];
        atomicAdd(ws_sum, (double)tv);
        atomicAdd(ws_cnt, (unsigned long long)tc);
    }
}

__global__ void rsl_final(const double* __restrict__ ws_sum,
                          const unsigned long long* __restrict__ ws_cnt,
                          float* __restrict__ out)
{
    if (threadIdx.x == 0) {
        double c = (double)ws_cnt[0];
        out[0] = (float)(ws_sum[0] / (c > 0.0 ? c : 1.0));
    }
}

extern "C" void kernel_launch(void* const* d_in, const int* in_sizes, int n_in,
                              void* d_out, int out_size, void* d_ws, size_t ws_size,
                              hipStream_t stream)
{
    const float* pred = (const float*)d_in[0];   // (4, 512, 256, 256) fp32
    const float* cls  = (const float*)d_in[1];   // (150, 512) fp32
    const int*   idx  = (const int*)d_in[2];     // (4, 1, 256, 256) int32
    const int*   lut  = (const int*)d_in[3];     // (512,) int32
    float* out = (float*)d_out;

    double* wsd = (double*)d_ws;
    unsigned long long* wsc = (unsigned long long*)((char*)d_ws + 8);
    unsigned short* packed = (unsigned short*)((char*)d_ws + 1024);  // 160 KB

    rsl_pack_cls<<<40, 256, 0, stream>>>(cls, packed, wsd, wsc);

    const int total = 4 * HW_DIM;                 // 262144 pixels
    rsl_mfma<<<total / 128, 256, 0, stream>>>(pred, packed, idx, lut, wsd, wsc);
    rsl_final<<<1, 64, 0, stream>>>(wsd, wsc, out);
}

// Round 8
// 144.383 us; speedup vs baseline: 1.4477x; 1.4477x over previous
//
#include <hip/hip_runtime.h>
#include <hip/hip_bf16.h>

// RelativeSemanticLoss via bf16 MFMA GEMM + fused softmax-NLL epilogue.
// R8: counted-vmcnt pipeline (T3/T4): 3-buffer pred LDS staged by async DMA,
// raw s_barrier + s_waitcnt vmcnt(4) (never 0 mid-loop), cls prefetched
// 1 tile ahead into registers. Pred LDS XOR-swizzled (T2), src pre-swizzled.

#define NUM_CLS 150
#define NT_TILES 10      // 160 padded classes
#define D_DIM   512
#define HW_DIM  65536
#define IGNORE_L 255

typedef __attribute__((ext_vector_type(8))) short bf16x8;
typedef __attribute__((ext_vector_type(4))) float f32x4;
typedef __attribute__((ext_vector_type(4))) unsigned int u32x4;

#define GLOAD16(gsrc, ldst) \
    __builtin_amdgcn_global_load_lds((const __attribute__((address_space(1))) void*)(gsrc), \
                                     (__attribute__((address_space(3))) void*)(ldst), 16, 0, 0)

static __device__ __forceinline__ short f2bf(float f) {
    __hip_bfloat16 h = __float2bfloat16(f);   // RNE
    return __builtin_bit_cast(short, h);
}

// Pack cls (150x512 fp32) -> bf16 fragments in lane-linear order:
// packed[(s*10+nt)*512 + l*8 + j] (ushort) = bf16(cls[nt*16+(l&15)][s*32+(l>>4)*8+j])
// Also zeroes the ws accumulators.
__global__ void rsl_pack_cls(const float* __restrict__ cls,
                             unsigned short* __restrict__ packed,
                             double* __restrict__ ws_sum,
                             unsigned long long* __restrict__ ws_cnt)
{
    int t = blockIdx.x * 256 + threadIdx.x;      // 0 .. 16*10*64-1
    if (t == 0) { ws_sum[0] = 0.0; ws_cnt[0] = 0ull; }
    if (t >= 16 * NT_TILES * 64) return;
    int s  = t / (NT_TILES * 64);
    int r  = t - s * (NT_TILES * 64);
    int nt = r >> 6;
    int l  = r & 63;
    int c  = nt * 16 + (l & 15);
    int k  = s * 32 + (l >> 4) * 8;
    unsigned short v[8];
#pragma unroll
    for (int j = 0; j < 8; ++j)
        v[j] = (c < NUM_CLS) ? (unsigned short)f2bf(cls[c * D_DIM + k + j]) : (unsigned short)0;
    u32x4 w;
#pragma unroll
    for (int q = 0; q < 4; ++q)
        w[q] = (unsigned int)v[2 * q] | ((unsigned int)v[2 * q + 1] << 16);
    *(u32x4*)(packed + (size_t)(s * NT_TILES + nt) * 512 + (size_t)l * 8) = w;
}

__global__ __launch_bounds__(256, 2)
void rsl_mfma(const float* __restrict__ pred,
              const unsigned short* __restrict__ packed,
              const int*   __restrict__ idx,
              const int*   __restrict__ lut,
              double* __restrict__ ws_sum,
              unsigned long long* __restrict__ ws_cnt)
{
    // 3-buffer pred tile [32 dims][128 px] fp32, XOR-swizzled: [d][p ^ ((d>>3)<<3)]
    __shared__ float sP[3][32][128];   // 48 KB

    const int lane = threadIdx.x & 63;
    const int wid  = threadIdx.x >> 6;
    const int row  = lane & 15;      // M-idx in A-frag / N-idx in C/D
    const int g    = lane >> 4;      // k-group in A-frag / row-group in C/D

    const int pixbase = blockIdx.x * 128;        // never straddles b (65536%128==0)
    const int b  = pixbase >> 16;
    const int p0 = pixbase & 0xFFFF;
    const float* predb = pred + (size_t)b * D_DIM * HW_DIM;
    const int pxl = (lane & 31) * 4;             // float offset within tile row
    const int dl  = lane >> 5;                   // which of the 2 dims per DMA op

    f32x4 acc[2][NT_TILES] = {};
    bf16x8 cfA[NT_TILES], cfB[NT_TILES];

// stage pred tile ss -> buffer q: 4 DMA ops/wave, 16 total, src pre-swizzled
#define STAGE(ss, q) do { \
    _Pragma("unroll") \
    for (int tt = 0; tt < 4; ++tt) { \
        const int t_ = wid * 4 + tt; \
        GLOAD16(predb + (size_t)((ss) * 32 + 2 * t_ + dl) * HW_DIM \
                      + (p0 + (pxl ^ ((t_ >> 2) << 3))), \
                &sP[q][2 * t_][0]); \
    } } while (0)

// cls fragments for tile ss -> register array (10 x dwordx4, L2-resident)
#define LOADCLS(ss, cf) do { \
    const unsigned short* cb_ = packed + (size_t)((ss) * NT_TILES) * 512 + (size_t)lane * 8; \
    _Pragma("unroll") \
    for (int nt = 0; nt < NT_TILES; ++nt) cf[nt] = *(const bf16x8*)(cb_ + nt * 512); \
    } while (0)

    // prologue: issue order [cls0 x10][P0 x4][P1 x4], fenced to pin vmem order
    LOADCLS(0, cfA);
    asm volatile("" ::: "memory");
    STAGE(0, 0);
    asm volatile("" ::: "memory");
    STAGE(1, 1);

// one pipeline iteration. Invariant at entry: outstanding vmem (oldest first)
// = [P(s) 4][cls(s) 10][P(s+1) 4] -> vmcnt(4) completes tile-s data, keeps
// P(s+1) in flight. Issue [cls(s+1)][P(s+2)] after the barrier.
#define ITER(s, CUR, NXT) do { \
    if ((s) < 15) asm volatile("s_waitcnt vmcnt(4)" ::: "memory"); \
    else          asm volatile("s_waitcnt vmcnt(0)" ::: "memory"); \
    __builtin_amdgcn_sched_barrier(0); \
    __builtin_amdgcn_s_barrier(); \
    __builtin_amdgcn_sched_barrier(0); \
    if ((s) + 1 < 16) { LOADCLS((s) + 1, NXT); } \
    asm volatile("" ::: "memory"); \
    if ((s) + 2 < 16) { STAGE((s) + 2, ((s) + 2) % 3); } \
    bf16x8 pf[2]; \
    _Pragma("unroll") \
    for (int mt = 0; mt < 2; ++mt) \
        _Pragma("unroll") \
        for (int j = 0; j < 8; ++j) \
            pf[mt][j] = f2bf(sP[(s) % 3][g * 8 + j][(wid * 32 + mt * 16 + row) ^ (g << 3)]); \
    _Pragma("unroll") \
    for (int nt = 0; nt < NT_TILES; ++nt) { \
        _Pragma("unroll") \
        for (int mt = 0; mt < 2; ++mt) \
            acc[mt][nt] = __builtin_amdgcn_mfma_f32_16x16x32_bf16(pf[mt], CUR[nt], acc[mt][nt], 0, 0, 0); \
    } } while (0)

#pragma unroll
    for (int h = 0; h < 8; ++h) {
        ITER(2 * h,     cfA, cfB);
        ITER(2 * h + 1, cfB, cfA);
    }

    // ---- epilogue. C/D: class = nt*16 + row, pixel = wid*32 + mt*16 + g*4 + j ----
    const float invT = 1.0f / 0.07f;
    float local_sum = 0.f;
    int   local_cnt = 0;
#pragma unroll
    for (int mt = 0; mt < 2; ++mt) {
#pragma unroll
        for (int j = 0; j < 4; ++j) {
            const int pixg = pixbase + wid * 32 + mt * 16 + g * 4 + j;
            const int lab  = lut[idx[pixg]];
            const bool valid = (lab != IGNORE_L);

            float m = -1e30f;
#pragma unroll
            for (int nt = 0; nt < NT_TILES; ++nt) {
                int c = nt * 16 + row;
                float v = (c < NUM_CLS) ? acc[mt][nt][j] : -1e30f;
                m = fmaxf(m, v);
            }
#pragma unroll
            for (int o = 8; o >= 1; o >>= 1) m = fmaxf(m, __shfl_xor(m, o));

            float ssum = 0.f, slab = 0.f;
#pragma unroll
            for (int nt = 0; nt < NT_TILES; ++nt) {
                int c = nt * 16 + row;
                if (c < NUM_CLS) {
                    float v = acc[mt][nt][j];
                    ssum += __expf((v - m) * invT);
                    slab += (c == lab) ? v : 0.f;
                }
            }
#pragma unroll
            for (int o = 8; o >= 1; o >>= 1) {
                ssum += __shfl_xor(ssum, o);
                slab += __shfl_xor(slab, o);
            }
            if (row == 0 && valid) {
                local_sum += (m - slab) * invT + __logf(ssum);
                local_cnt += 1;
            }
        }
    }

    // wave(64) reduce -> block -> global atomics
#pragma unroll
    for (int o = 32; o >= 1; o >>= 1) {
        local_sum += __shfl_down(local_sum, o);
        local_cnt += __shfl_down(local_cnt, o);
    }
    __shared__ float sv[4];
    __shared__ int   sc[4];
    if (lane == 0) { sv[wid] = local_sum; sc[wid] = local_cnt; }
    __syncthreads();
    if (threadIdx.x == 0) {
        float tv = sv[0] + sv[1] + sv[2] + sv[3];
        int   tc = sc[0] + sc[1] + sc[2] + sc[3];
        atomicAdd(ws_sum, (double)tv);
        atomicAdd(ws_cnt, (unsigned long long)tc);
    }
}

__global__ void rsl_final(const double* __restrict__ ws_sum,
                          const unsigned long long* __restrict__ ws_cnt,
                          float* __restrict__ out)
{
    if (threadIdx.x == 0) {
        double c = (double)ws_cnt[0];
        out[0] = (float)(ws_sum[0] / (c > 0.0 ? c : 1.0));
    }
}

extern "C" void kernel_launch(void* const* d_in, const int* in_sizes, int n_in,
                              void* d_out, int out_size, void* d_ws, size_t ws_size,
                              hipStream_t stream)
{
    const float* pred = (const float*)d_in[0];   // (4, 512, 256, 256) fp32
    const float* cls  = (const float*)d_in[1];   // (150, 512) fp32
    const int*   idx  = (const int*)d_in[2];     // (4, 1, 256, 256) int32
    const int*   lut  = (const int*)d_in[3];     // (512,) int32
    float* out = (float*)d_out;

    double* wsd = (double*)d_ws;
    unsigned long long* wsc = (unsigned long long*)((char*)d_ws + 8);
    unsigned short* packed = (unsigned short*)((char*)d_ws + 1024);  // 160 KB

    rsl_pack_cls<<<40, 256, 0, stream>>>(cls, packed, wsd, wsc);

    const int total = 4 * HW_DIM;                 // 262144 pixels
    rsl_mfma<<<total / 128, 256, 0, stream>>>(pred, packed, idx, lut, wsd, wsc);
    rsl_final<<<1, 64, 0, stream>>>(wsd, wsc, out);
}

// Round 9
// 139.197 us; speedup vs baseline: 1.5017x; 1.0373x over previous
//
#include <hip/hip_runtime.h>
#include <hip/hip_bf16.h>

// RelativeSemanticLoss via bf16 MFMA GEMM + fused softmax-NLL epilogue.
// R9: R4 data path (pred+cls staged via async global_load_lds) with a clean
// counted-vmcnt pipeline: pred 3-buf, cls 2-buf, s_waitcnt vmcnt(4) + raw
// s_barrier per iter (pred prefetch never drains mid-loop). Pred LDS
// XOR-swizzled via pre-swizzled global source (rule #21). No sched_barrier.

#define NUM_CLS 150
#define NT_TILES 10      // 160 padded classes
#define D_DIM   512
#define HW_DIM  65536
#define IGNORE_L 255

typedef __attribute__((ext_vector_type(8))) short bf16x8;
typedef __attribute__((ext_vector_type(4))) float f32x4;
typedef __attribute__((ext_vector_type(4))) unsigned int u32x4;

#define GLOAD16(gsrc, ldst) \
    __builtin_amdgcn_global_load_lds((const __attribute__((address_space(1))) void*)(gsrc), \
                                     (__attribute__((address_space(3))) void*)(ldst), 16, 0, 0)

static __device__ __forceinline__ short f2bf(float f) {
    __hip_bfloat16 h = __float2bfloat16(f);   // RNE
    return __builtin_bit_cast(short, h);
}

// Pack cls (150x512 fp32) -> bf16 fragments in lane-linear order:
// packed[(s*10+nt)*512 + l*8 + j] (ushort) = bf16(cls[nt*16+(l&15)][s*32+(l>>4)*8+j])
// Also zeroes the ws accumulators.
__global__ void rsl_pack_cls(const float* __restrict__ cls,
                             unsigned short* __restrict__ packed,
                             double* __restrict__ ws_sum,
                             unsigned long long* __restrict__ ws_cnt)
{
    int t = blockIdx.x * 256 + threadIdx.x;      // 0 .. 16*10*64-1
    if (t == 0) { ws_sum[0] = 0.0; ws_cnt[0] = 0ull; }
    if (t >= 16 * NT_TILES * 64) return;
    int s  = t / (NT_TILES * 64);
    int r  = t - s * (NT_TILES * 64);
    int nt = r >> 6;
    int l  = r & 63;
    int c  = nt * 16 + (l & 15);
    int k  = s * 32 + (l >> 4) * 8;
    unsigned short v[8];
#pragma unroll
    for (int j = 0; j < 8; ++j)
        v[j] = (c < NUM_CLS) ? (unsigned short)f2bf(cls[c * D_DIM + k + j]) : (unsigned short)0;
    u32x4 w;
#pragma unroll
    for (int q = 0; q < 4; ++q)
        w[q] = (unsigned int)v[2 * q] | ((unsigned int)v[2 * q + 1] << 16);
    *(u32x4*)(packed + (size_t)(s * NT_TILES + nt) * 512 + (size_t)l * 8) = w;
}

__global__ __launch_bounds__(256, 2)
void rsl_mfma(const float* __restrict__ pred,
              const unsigned short* __restrict__ packed,
              const int*   __restrict__ idx,
              const int*   __restrict__ lut,
              double* __restrict__ ws_sum,
              unsigned long long* __restrict__ ws_cnt)
{
    // pred tile [32 dims][128 px] fp32 swizzled ([d][p ^ ((d>>3)<<3)]), 3 bufs;
    // cls tile [10 nt][512] ushort, 2 bufs. 48KB + 20KB = 68KB -> 2 blocks/CU.
    __shared__ float          sP[3][32][128];
    __shared__ unsigned short sC[2][NT_TILES][512];

    const int lane = threadIdx.x & 63;
    const int wid  = threadIdx.x >> 6;
    const int row  = lane & 15;      // M-idx in A-frag / N-idx in C/D
    const int g    = lane >> 4;      // k-group in A-frag / row-group in C/D

    const int pixbase = blockIdx.x * 128;        // never straddles b (65536%128==0)
    const int b  = pixbase >> 16;
    const int p0 = pixbase & 0xFFFF;
    const float* predb = pred + (size_t)b * D_DIM * HW_DIM;
    const int pxl = (lane & 31) * 4;             // float offset within tile row
    const int dl  = lane >> 5;                   // which of the 2 dims per DMA op

    f32x4 acc[2][NT_TILES] = {};

// stage pred K-tile ss -> buffer ss%3 (4 DMA/wave, 16 total, src pre-swizzled)
#define STAGEP(ss) do { \
    const float* srcb_ = predb + (size_t)((ss) * 32) * HW_DIM; \
    _Pragma("unroll") \
    for (int tt = 0; tt < 4; ++tt) { \
        const int t_ = wid * 4 + tt; \
        GLOAD16(srcb_ + (size_t)(2 * t_ + dl) * HW_DIM + (p0 + (pxl ^ ((t_ >> 2) << 3))), \
                &sP[(ss) % 3][2 * t_][0]); \
    } } while (0)

// stage cls K-tile ss -> buffer ss&1 (2-3 DMA/wave; uneven ok, vmcnt counts from newest)
#define STAGEC(ss) do { \
    for (int nt = wid; nt < NT_TILES; nt += 4) \
        GLOAD16(packed + (size_t)((ss) * NT_TILES + nt) * 512 + (size_t)lane * 8, \
                &sC[(ss) & 1][nt][0]); \
    } while (0)

#define COMPUTE(s) do { \
    const int pb_ = (s) % 3; const int cb_ = (s) & 1; \
    bf16x8 pf[2]; \
    _Pragma("unroll") \
    for (int mt = 0; mt < 2; ++mt) \
        _Pragma("unroll") \
        for (int j = 0; j < 8; ++j) \
            pf[mt][j] = f2bf(sP[pb_][g * 8 + j][(wid * 32 + mt * 16 + row) ^ (g << 3)]); \
    _Pragma("unroll") \
    for (int nt = 0; nt < NT_TILES; ++nt) { \
        bf16x8 cf = *(const bf16x8*)&sC[cb_][nt][lane * 8]; \
        _Pragma("unroll") \
        for (int mt = 0; mt < 2; ++mt) \
            acc[mt][nt] = __builtin_amdgcn_mfma_f32_16x16x32_bf16(pf[mt], cf, acc[mt][nt], 0, 0, 0); \
    } } while (0)

    // prologue: issue order [cls(0)][pred(0)][pred(1)] -> newest 4 = pred(1)
    STAGEC(0);
    asm volatile("" ::: "memory");
    STAGEP(0);
    asm volatile("" ::: "memory");
    STAGEP(1);

    // steady state: entry outstanding (oldest first) = [..][pred(s)][cls(s)][pred(s+1)]
    // vmcnt(4) completes everything except pred(s+1); barrier makes all waves' DMA visible.
    for (int s = 0; s < 14; ++s) {
        asm volatile("s_waitcnt vmcnt(4)" ::: "memory");
        __builtin_amdgcn_s_barrier();
        asm volatile("" ::: "memory");
        STAGEC(s + 1);
        asm volatile("" ::: "memory");
        STAGEP(s + 2);
        asm volatile("" ::: "memory");
        COMPUTE(s);
    }
    // s = 14: no pred(16); issue cls(15) only
    asm volatile("s_waitcnt vmcnt(4)" ::: "memory");
    __builtin_amdgcn_s_barrier();
    asm volatile("" ::: "memory");
    STAGEC(15);
    asm volatile("" ::: "memory");
    COMPUTE(14);
    // s = 15: final drain
    asm volatile("s_waitcnt vmcnt(0)" ::: "memory");
    __builtin_amdgcn_s_barrier();
    asm volatile("" ::: "memory");
    COMPUTE(15);

    // ---- epilogue. C/D: class = nt*16 + row, pixel = wid*32 + mt*16 + g*4 + j ----
    const float invT = 1.0f / 0.07f;
    float local_sum = 0.f;
    int   local_cnt = 0;
#pragma unroll
    for (int mt = 0; mt < 2; ++mt) {
#pragma unroll
        for (int j = 0; j < 4; ++j) {
            const int pixg = pixbase + wid * 32 + mt * 16 + g * 4 + j;
            const int lab  = lut[idx[pixg]];
            const bool valid = (lab != IGNORE_L);

            float m = -1e30f;
#pragma unroll
            for (int nt = 0; nt < NT_TILES; ++nt) {
                int c = nt * 16 + row;
                float v = (c < NUM_CLS) ? acc[mt][nt][j] : -1e30f;
                m = fmaxf(m, v);
            }
#pragma unroll
            for (int o = 8; o >= 1; o >>= 1) m = fmaxf(m, __shfl_xor(m, o));

            float ssum = 0.f, slab = 0.f;
#pragma unroll
            for (int nt = 0; nt < NT_TILES; ++nt) {
                int c = nt * 16 + row;
                if (c < NUM_CLS) {
                    float v = acc[mt][nt][j];
                    ssum += __expf((v - m) * invT);
                    slab += (c == lab) ? v : 0.f;
                }
            }
#pragma unroll
            for (int o = 8; o >= 1; o >>= 1) {
                ssum += __shfl_xor(ssum, o);
                slab += __shfl_xor(slab, o);
            }
            if (row == 0 && valid) {
                local_sum += (m - slab) * invT + __logf(ssum);
                local_cnt += 1;
            }
        }
    }

    // wave(64) reduce -> block -> global atomics
#pragma unroll
    for (int o = 32; o >= 1; o >>= 1) {
        local_sum += __shfl_down(local_sum, o);
        local_cnt += __shfl_down(local_cnt, o);
    }
    __shared__ float sv[4];
    __shared__ int   sc[4];
    if (lane == 0) { sv[wid] = local_sum; sc[wid] = local_cnt; }
    __syncthreads();
    if (threadIdx.x == 0) {
        float tv = sv[0] + sv[1] + sv[2] + sv[3];
        int   tc = sc[0] + sc[1] + sc[2] + sc[3];
        atomicAdd(ws_sum, (double)tv);
        atomicAdd(ws_cnt, (unsigned long long)tc);
    }
}

__global__ void rsl_final(const double* __restrict__ ws_sum,
                          const unsigned long long* __restrict__ ws_cnt,
                          float* __restrict__ out)
{
    if (threadIdx.x == 0) {
        double c = (double)ws_cnt[0];
        out[0] = (float)(ws_sum[0] / (c > 0.0 ? c : 1.0));
    }
}

extern "C" void kernel_launch(void* const* d_in, const int* in_sizes, int n_in,
                              void* d_out, int out_size, void* d_ws, size_t ws_size,
                              hipStream_t stream)
{
    const float* pred = (const float*)d_in[0];   // (4, 512, 256, 256) fp32
    const float* cls  = (const float*)d_in[1];   // (150, 512) fp32
    const int*   idx  = (const int*)d_in[2];     // (4, 1, 256, 256) int32
    const int*   lut  = (const int*)d_in[3];     // (512,) int32
    float* out = (float*)d_out;

    double* wsd = (double*)d_ws;
    unsigned long long* wsc = (unsigned long long*)((char*)d_ws + 8);
    unsigned short* packed = (unsigned short*)((char*)d_ws + 1024);  // 160 KB

    rsl_pack_cls<<<40, 256, 0, stream>>>(cls, packed, wsd, wsc);

    const int total = 4 * HW_DIM;                 // 262144 pixels
    rsl_mfma<<<total / 128, 256, 0, stream>>>(pred, packed, idx, lut, wsd, wsc);
    rsl_final<<<1, 64, 0, stream>>>(wsd, wsc, out);
}

// Round 10
// 135.406 us; speedup vs baseline: 1.5437x; 1.0280x over previous
//
#include <hip/hip_runtime.h>
#include <hip/hip_bf16.h>

// RelativeSemanticLoss via bf16 MFMA GEMM + fused softmax-NLL epilogue.
// R10: exact R6 structure (16x16x32 MFMA, async global_load_lds dbuf,
// 3 blk/CU) + ONE change: bijective XCD-chunked block swizzle (T1) so
// concurrent blocks on one XCD read adjacent 512B segments (DRAM page hits).

#define NUM_CLS 150
#define NT_TILES 10      // 160 padded classes
#define D_DIM   512
#define HW_DIM  65536
#define IGNORE_L 255

typedef __attribute__((ext_vector_type(8))) short bf16x8;
typedef __attribute__((ext_vector_type(4))) float f32x4;
typedef __attribute__((ext_vector_type(4))) unsigned int u32x4;

#define GLOAD16(gsrc, ldst) \
    __builtin_amdgcn_global_load_lds((const __attribute__((address_space(1))) void*)(gsrc), \
                                     (__attribute__((address_space(3))) void*)(ldst), 16, 0, 0)

static __device__ __forceinline__ short f2bf(float f) {
    __hip_bfloat16 h = __float2bfloat16(f);   // RNE
    return __builtin_bit_cast(short, h);
}

// Pack cls (150x512 fp32) -> bf16 fragments in lane-linear order:
// packed[(s*10+nt)*512 + l*8 + j] (ushort) = bf16(cls[nt*16+(l&15)][s*32+(l>>4)*8+j])
// Also zeroes the ws accumulators.
__global__ void rsl_pack_cls(const float* __restrict__ cls,
                             unsigned short* __restrict__ packed,
                             double* __restrict__ ws_sum,
                             unsigned long long* __restrict__ ws_cnt)
{
    int t = blockIdx.x * 256 + threadIdx.x;      // 0 .. 16*10*64-1
    if (t == 0) { ws_sum[0] = 0.0; ws_cnt[0] = 0ull; }
    if (t >= 16 * NT_TILES * 64) return;
    int s  = t / (NT_TILES * 64);
    int r  = t - s * (NT_TILES * 64);
    int nt = r >> 6;
    int l  = r & 63;
    int c  = nt * 16 + (l & 15);
    int k  = s * 32 + (l >> 4) * 8;
    unsigned short v[8];
#pragma unroll
    for (int j = 0; j < 8; ++j)
        v[j] = (c < NUM_CLS) ? (unsigned short)f2bf(cls[c * D_DIM + k + j]) : (unsigned short)0;
    u32x4 w;
#pragma unroll
    for (int q = 0; q < 4; ++q)
        w[q] = (unsigned int)v[2 * q] | ((unsigned int)v[2 * q + 1] << 16);
    *(u32x4*)(packed + (size_t)(s * NT_TILES + nt) * 512 + (size_t)l * 8) = w;
}

__global__ __launch_bounds__(256, 3)
void rsl_mfma(const float* __restrict__ pred,
              const unsigned short* __restrict__ packed,
              const int*   __restrict__ idx,
              const int*   __restrict__ lut,
              double* __restrict__ ws_sum,
              unsigned long long* __restrict__ ws_cnt)
{
    // LDS: pred tile [32 dims][128 pixels] fp32 (16KB) x2 + cls tile 10KB x2 = 52KB
    __shared__ float          sP[2][32][128];
    __shared__ unsigned short sC[2][NT_TILES][512];

    const int lane = threadIdx.x & 63;
    const int wid  = threadIdx.x >> 6;
    const int row  = lane & 15;      // M-idx in tile (A frag) / N-idx (C/D)
    const int g    = lane >> 4;      // k-group (A frag) / row-group (C/D)

    // T1: bijective XCD-chunked swizzle. nwg = 2048 (divisible by 8):
    // XCD k (= orig%8) gets the contiguous chunk [k*256, (k+1)*256).
    const int wg = (blockIdx.x & 7) * 256 + (blockIdx.x >> 3);

    const int pixbase = wg * 128;                    // never straddles b (65536%128==0)
    const int b  = pixbase >> 16;
    const int p0 = pixbase & 0xFFFF;
    // staging: lane covers dim-offset (lane>>5), pixels (lane&31)*4 .. +3 (16B)
    const float* pstage = pred + (size_t)b * D_DIM * HW_DIM
                        + (size_t)(lane >> 5) * HW_DIM + (p0 + (lane & 31) * 4);

    f32x4 acc[2][NT_TILES] = {};

    // ---- prologue: stage s=0 ----
    {
#pragma unroll
        for (int tt = 0; tt < 4; ++tt) {
            const int t = wid * 4 + tt;              // dim pair index 0..15
            GLOAD16(pstage + (size_t)(2 * t) * HW_DIM, &sP[0][2 * t][0]);
        }
        for (int nt = wid; nt < NT_TILES; nt += 4)
            GLOAD16(packed + (size_t)nt * 512 + (size_t)lane * 8, &sC[0][nt][0]);
    }
    __syncthreads();

    for (int s = 0; s < 16; ++s) {
        const int cur = s & 1;
        // ---- stage s+1 into the other buffer (async) ----
        if (s < 15) {
            const float* srcb = pstage + (size_t)((s + 1) * 32) * HW_DIM;
#pragma unroll
            for (int tt = 0; tt < 4; ++tt) {
                const int t = wid * 4 + tt;
                GLOAD16(srcb + (size_t)(2 * t) * HW_DIM, &sP[cur ^ 1][2 * t][0]);
            }
            const unsigned short* csrc = packed + (size_t)((s + 1) * NT_TILES) * 512 + (size_t)lane * 8;
            for (int nt = wid; nt < NT_TILES; nt += 4)
                GLOAD16(csrc + (size_t)nt * 512, &sC[cur ^ 1][nt][0]);
        }

        // ---- compute on current buffer ----
        bf16x8 pf[2];
#pragma unroll
        for (int mt = 0; mt < 2; ++mt)
#pragma unroll
            for (int j = 0; j < 8; ++j)
                pf[mt][j] = f2bf(sP[cur][g * 8 + j][wid * 32 + mt * 16 + row]);

#pragma unroll
        for (int nt = 0; nt < NT_TILES; ++nt) {
            bf16x8 cf = *(const bf16x8*)&sC[cur][nt][lane * 8];
#pragma unroll
            for (int mt = 0; mt < 2; ++mt)
                acc[mt][nt] = __builtin_amdgcn_mfma_f32_16x16x32_bf16(pf[mt], cf, acc[mt][nt], 0, 0, 0);
        }
        __syncthreads();   // drain (vmcnt0+lgkm0) + barrier: next tile ready, buffers safe
    }

    // ---- epilogue. C/D: class = nt*16 + row, pixel = wid*32 + mt*16 + g*4 + j ----
    const float invT = 1.0f / 0.07f;
    float local_sum = 0.f;
    int   local_cnt = 0;
#pragma unroll
    for (int mt = 0; mt < 2; ++mt) {
#pragma unroll
        for (int j = 0; j < 4; ++j) {
            const int pixg = pixbase + wid * 32 + mt * 16 + g * 4 + j;
            const int lab  = lut[idx[pixg]];
            const bool valid = (lab != IGNORE_L);

            float m = -1e30f;
#pragma unroll
            for (int nt = 0; nt < NT_TILES; ++nt) {
                int c = nt * 16 + row;
                float v = (c < NUM_CLS) ? acc[mt][nt][j] : -1e30f;
                m = fmaxf(m, v);
            }
#pragma unroll
            for (int o = 8; o >= 1; o >>= 1) m = fmaxf(m, __shfl_xor(m, o));

            float ssum = 0.f, slab = 0.f;
#pragma unroll
            for (int nt = 0; nt < NT_TILES; ++nt) {
                int c = nt * 16 + row;
                if (c < NUM_CLS) {
                    float v = acc[mt][nt][j];
                    ssum += __expf((v - m) * invT);
                    slab += (c == lab) ? v : 0.f;
                }
            }
#pragma unroll
            for (int o = 8; o >= 1; o >>= 1) {
                ssum += __shfl_xor(ssum, o);
                slab += __shfl_xor(slab, o);
            }
            if (row == 0 && valid) {
                local_sum += (m - slab) * invT + __logf(ssum);
                local_cnt += 1;
            }
        }
    }

    // wave(64) reduce -> block -> global atomics
#pragma unroll
    for (int o = 32; o >= 1; o >>= 1) {
        local_sum += __shfl_down(local_sum, o);
        local_cnt += __shfl_down(local_cnt, o);
    }
    __shared__ float sv[4];
    __shared__ int   sc[4];
    if (lane == 0) { sv[wid] = local_sum; sc[wid] = local_cnt; }
    __syncthreads();
    if (threadIdx.x == 0) {
        float tv = sv[0] + sv[1] + sv[2] + sv[3];
        int   tc = sc[0] + sc[1] + sc[2] + sc[3];
        atomicAdd(ws_sum, (double)tv);
        atomicAdd(ws_cnt, (unsigned long long)tc);
    }
}

__global__ void rsl_final(const double* __restrict__ ws_sum,
                          const unsigned long long* __restrict__ ws_cnt,
                          float* __restrict__ out)
{
    if (threadIdx.x == 0) {
        double c = (double)ws_cnt[0];
        out[0] = (float)(ws_sum[0] / (c > 0.0 ? c : 1.0));
    }
}

extern "C" void kernel_launch(void* const* d_in, const int* in_sizes, int n_in,
                              void* d_out, int out_size, void* d_ws, size_t ws_size,
                              hipStream_t stream)
{
    const float* pred = (const float*)d_in[0];   // (4, 512, 256, 256) fp32
    const float* cls  = (const float*)d_in[1];   // (150, 512) fp32
    const int*   idx  = (const int*)d_in[2];     // (4, 1, 256, 256) int32
    const int*   lut  = (const int*)d_in[3];     // (512,) int32
    float* out = (float*)d_out;

    double* wsd = (double*)d_ws;
    unsigned long long* wsc = (unsigned long long*)((char*)d_ws + 8);
    unsigned short* packed = (unsigned short*)((char*)d_ws + 1024);  // 160 KB

    rsl_pack_cls<<<40, 256, 0, stream>>>(cls, packed, wsd, wsc);

    const int total = 4 * HW_DIM;                 // 262144 pixels
    rsl_mfma<<<total / 128, 256, 0, stream>>>(pred, packed, idx, lut, wsd, wsc);
    rsl_final<<<1, 64, 0, stream>>>(wsd, wsc, out);
}

// Round 11
// 129.547 us; speedup vs baseline: 1.6135x; 1.0452x over previous
//
#include <hip/hip_runtime.h>
#include <hip/hip_bf16.h>

// RelativeSemanticLoss via bf16 MFMA GEMM + fused softmax-NLL epilogue.
// R11: exact R6 structure (16x16x32 MFMA, async global_load_lds dbuf,
// 3 blk/CU, plain __syncthreads 2-phase) + ONE change: pred LDS XOR-swizzle
// [d][p ^ ((d>>3)<<3)] via pre-swizzled global source (rule #21).
// Read conflict drops 4-way -> 2-way (free, m136).

#define NUM_CLS 150
#define NT_TILES 10      // 160 padded classes
#define D_DIM   512
#define HW_DIM  65536
#define IGNORE_L 255

typedef __attribute__((ext_vector_type(8))) short bf16x8;
typedef __attribute__((ext_vector_type(4))) float f32x4;
typedef __attribute__((ext_vector_type(4))) unsigned int u32x4;

#define GLOAD16(gsrc, ldst) \
    __builtin_amdgcn_global_load_lds((const __attribute__((address_space(1))) void*)(gsrc), \
                                     (__attribute__((address_space(3))) void*)(ldst), 16, 0, 0)

static __device__ __forceinline__ short f2bf(float f) {
    __hip_bfloat16 h = __float2bfloat16(f);   // RNE
    return __builtin_bit_cast(short, h);
}

// Pack cls (150x512 fp32) -> bf16 fragments in lane-linear order:
// packed[(s*10+nt)*512 + l*8 + j] (ushort) = bf16(cls[nt*16+(l&15)][s*32+(l>>4)*8+j])
// Also zeroes the ws accumulators.
__global__ void rsl_pack_cls(const float* __restrict__ cls,
                             unsigned short* __restrict__ packed,
                             double* __restrict__ ws_sum,
                             unsigned long long* __restrict__ ws_cnt)
{
    int t = blockIdx.x * 256 + threadIdx.x;      // 0 .. 16*10*64-1
    if (t == 0) { ws_sum[0] = 0.0; ws_cnt[0] = 0ull; }
    if (t >= 16 * NT_TILES * 64) return;
    int s  = t / (NT_TILES * 64);
    int r  = t - s * (NT_TILES * 64);
    int nt = r >> 6;
    int l  = r & 63;
    int c  = nt * 16 + (l & 15);
    int k  = s * 32 + (l >> 4) * 8;
    unsigned short v[8];
#pragma unroll
    for (int j = 0; j < 8; ++j)
        v[j] = (c < NUM_CLS) ? (unsigned short)f2bf(cls[c * D_DIM + k + j]) : (unsigned short)0;
    u32x4 w;
#pragma unroll
    for (int q = 0; q < 4; ++q)
        w[q] = (unsigned int)v[2 * q] | ((unsigned int)v[2 * q + 1] << 16);
    *(u32x4*)(packed + (size_t)(s * NT_TILES + nt) * 512 + (size_t)l * 8) = w;
}

__global__ __launch_bounds__(256, 3)
void rsl_mfma(const float* __restrict__ pred,
              const unsigned short* __restrict__ packed,
              const int*   __restrict__ idx,
              const int*   __restrict__ lut,
              double* __restrict__ ws_sum,
              unsigned long long* __restrict__ ws_cnt)
{
    // LDS: pred tile [32 dims][128 px] fp32 (16KB) x2, SWIZZLED layout
    // ([d][p ^ ((d>>3)<<3)]); cls tile 10KB x2. Total 52KB -> 3 blocks/CU.
    __shared__ float          sP[2][32][128];
    __shared__ unsigned short sC[2][NT_TILES][512];

    const int lane = threadIdx.x & 63;
    const int wid  = threadIdx.x >> 6;
    const int row  = lane & 15;      // M-idx in tile (A frag) / N-idx (C/D)
    const int g    = lane >> 4;      // k-group (A frag) / row-group (C/D)

    const int pixbase = blockIdx.x * 128;            // never straddles b (65536%128==0)
    const int b  = pixbase >> 16;
    const int p0 = pixbase & 0xFFFF;
    const float* predb = pred + (size_t)b * D_DIM * HW_DIM;
    const int pxl = (lane & 31) * 4;                 // float offset in tile row
    const int dl  = lane >> 5;                       // which of the 2 dims per DMA op

    f32x4 acc[2][NT_TILES] = {};

// stage pred K-tile ss -> buffer q; instruction t covers dims {2t+dl},
// global pixel offset pre-swizzled by (t>>2)<<3 so linear LDS dest = swizzled layout
#define STAGEP(ss, q) do { \
    const float* srcb_ = predb + (size_t)((ss) * 32) * HW_DIM; \
    _Pragma("unroll") \
    for (int tt = 0; tt < 4; ++tt) { \
        const int t_ = wid * 4 + tt; \
        GLOAD16(srcb_ + (size_t)(2 * t_ + dl) * HW_DIM + (p0 + (pxl ^ ((t_ >> 2) << 3))), \
                &sP[q][2 * t_][0]); \
    } } while (0)

    // ---- prologue: stage s=0 ----
    STAGEP(0, 0);
    for (int nt = wid; nt < NT_TILES; nt += 4)
        GLOAD16(packed + (size_t)nt * 512 + (size_t)lane * 8, &sC[0][nt][0]);
    __syncthreads();

    for (int s = 0; s < 16; ++s) {
        const int cur = s & 1;
        // ---- stage s+1 into the other buffer (async) ----
        if (s < 15) {
            STAGEP(s + 1, cur ^ 1);
            const unsigned short* csrc = packed + (size_t)((s + 1) * NT_TILES) * 512 + (size_t)lane * 8;
            for (int nt = wid; nt < NT_TILES; nt += 4)
                GLOAD16(csrc + (size_t)nt * 512, &sC[cur ^ 1][nt][0]);
        }

        // ---- compute on current buffer (swizzled read: 2-way conflict = free) ----
        bf16x8 pf[2];
#pragma unroll
        for (int mt = 0; mt < 2; ++mt)
#pragma unroll
            for (int j = 0; j < 8; ++j)
                pf[mt][j] = f2bf(sP[cur][g * 8 + j][(wid * 32 + mt * 16 + row) ^ (g << 3)]);

#pragma unroll
        for (int nt = 0; nt < NT_TILES; ++nt) {
            bf16x8 cf = *(const bf16x8*)&sC[cur][nt][lane * 8];
#pragma unroll
            for (int mt = 0; mt < 2; ++mt)
                acc[mt][nt] = __builtin_amdgcn_mfma_f32_16x16x32_bf16(pf[mt], cf, acc[mt][nt], 0, 0, 0);
        }
        __syncthreads();   // drain + barrier: next tile ready, buffers safe
    }

    // ---- epilogue. C/D: class = nt*16 + row, pixel = wid*32 + mt*16 + g*4 + j ----
    const float invT = 1.0f / 0.07f;
    float local_sum = 0.f;
    int   local_cnt = 0;
#pragma unroll
    for (int mt = 0; mt < 2; ++mt) {
#pragma unroll
        for (int j = 0; j < 4; ++j) {
            const int pixg = pixbase + wid * 32 + mt * 16 + g * 4 + j;
            const int lab  = lut[idx[pixg]];
            const bool valid = (lab != IGNORE_L);

            float m = -1e30f;
#pragma unroll
            for (int nt = 0; nt < NT_TILES; ++nt) {
                int c = nt * 16 + row;
                float v = (c < NUM_CLS) ? acc[mt][nt][j] : -1e30f;
                m = fmaxf(m, v);
            }
#pragma unroll
            for (int o = 8; o >= 1; o >>= 1) m = fmaxf(m, __shfl_xor(m, o));

            float ssum = 0.f, slab = 0.f;
#pragma unroll
            for (int nt = 0; nt < NT_TILES; ++nt) {
                int c = nt * 16 + row;
                if (c < NUM_CLS) {
                    float v = acc[mt][nt][j];
                    ssum += __expf((v - m) * invT);
                    slab += (c == lab) ? v : 0.f;
                }
            }
#pragma unroll
            for (int o = 8; o >= 1; o >>= 1) {
                ssum += __shfl_xor(ssum, o);
                slab += __shfl_xor(slab, o);
            }
            if (row == 0 && valid) {
                local_sum += (m - slab) * invT + __logf(ssum);
                local_cnt += 1;
            }
        }
    }

    // wave(64) reduce -> block -> global atomics
#pragma unroll
    for (int o = 32; o >= 1; o >>= 1) {
        local_sum += __shfl_down(local_sum, o);
        local_cnt += __shfl_down(local_cnt, o);
    }
    __shared__ float sv[4];
    __shared__ int   sc[4];
    if (lane == 0) { sv[wid] = local_sum; sc[wid] = local_cnt; }
    __syncthreads();
    if (threadIdx.x == 0) {
        float tv = sv[0] + sv[1] + sv[2] + sv[3];
        int   tc = sc[0] + sc[1] + sc[2] + sc[3];
        atomicAdd(ws_sum, (double)tv);
        atomicAdd(ws_cnt, (unsigned long long)tc);
    }
}

__global__ void rsl_final(const double* __restrict__ ws_sum,
                          const unsigned long long* __restrict__ ws_cnt,
                          float* __restrict__ out)
{
    if (threadIdx.x == 0) {
        double c = (double)ws_cnt[0];
        out[0] = (float)(ws_sum[0] / (c > 0.0 ? c : 1.0));
    }
}

extern "C" void kernel_launch(void* const* d_in, const int* in_sizes, int n_in,
                              void* d_out, int out_size, void* d_ws, size_t ws_size,
                              hipStream_t stream)
{
    const float* pred = (const float*)d_in[0];   // (4, 512, 256, 256) fp32
    const float* cls  = (const float*)d_in[1];   // (150, 512) fp32
    const int*   idx  = (const int*)d_in[2];     // (4, 1, 256, 256) int32
    const int*   lut  = (const int*)d_in[3];     // (512,) int32
    float* out = (float*)d_out;

    double* wsd = (double*)d_ws;
    unsigned long long* wsc = (unsigned long long*)((char*)d_ws + 8);
    unsigned short* packed = (unsigned short*)((char*)d_ws + 1024);  // 160 KB

    rsl_pack_cls<<<40, 256, 0, stream>>>(cls, packed, wsd, wsc);

    const int total = 4 * HW_DIM;                 // 262144 pixels
    rsl_mfma<<<total / 128, 256, 0, stream>>>(pred, packed, idx, lut, wsd, wsc);
    rsl_final<<<1, 64, 0, stream>>>(wsd, wsc, out);
}